// Round 1
// baseline (23064.737 us; speedup 1.0000x reference)
//
#include <hip/hip_runtime.h>
#include <cstdint>
#include <cstddef>

#define Bz 64
#define Tz 512
#define Iz 512
#define Hz 512
#define Cz 4096

typedef __attribute__((ext_vector_type(8))) short short8;
typedef __attribute__((ext_vector_type(4))) float floatx4;

__device__ __forceinline__ unsigned short f2bf(float f) {
  union { float f; unsigned u; } v; v.f = f;
  unsigned r = v.u + 0x7fffu + ((v.u >> 16) & 1u);
  return (unsigned short)(r >> 16);
}
__device__ __forceinline__ float bf2f(unsigned short h) {
  union { unsigned u; float f; } v; v.u = ((unsigned)h) << 16; return v.f;
}
__device__ __forceinline__ float sigmoidf_(float x) { return 1.0f / (1.0f + __expf(-x)); }

// ---------------- precast kernels (packed path) ----------------

// Pack [Wi;Ws] into B-fragment order for kernel A:
// flat id = (((w*4 + nt)*32 + kt)*64 + lane), each unit = 8 bf16 along k.
__global__ __launch_bounds__(256) void precast_wpk(const float* __restrict__ Wi,
                                                   const float* __restrict__ Wst,
                                                   short* __restrict__ wpk) {
  int id = blockIdx.x * 256 + threadIdx.x;       // 0..2097151
  int l  = id & 63;
  int kt = (id >> 6) & 31;
  int nt = (id >> 11) & 3;
  int w  = id >> 13;
  int r  = nt * Cz + w * 16 + (l & 15);          // gate-row in (4C, .)
  int k  = kt * 32 + (l >> 4) * 8;               // 0..1023
  const float* p = (k < Iz) ? (Wi + (size_t)r * Iz + k)
                            : (Wst + (size_t)r * Hz + (k - Iz));
  short8 v;
  #pragma unroll
  for (int i = 0; i < 8; ++i) v[i] = (short)f2bf(p[i]);
  *(short8*)(wpk + (size_t)id * 8) = v;
}

// Pack Wp^T (B[k=c][n=j] = Wp[j][c]) fragment order for kernel B:
// flat id = (((kc*32 + jc)*16 + kt)*64 + lane)
__global__ __launch_bounds__(256) void precast_wpp(const float* __restrict__ Wp,
                                                   short* __restrict__ wpp) {
  int id = blockIdx.x * 256 + threadIdx.x;       // 0..262143
  int l  = id & 63;
  int kt = (id >> 6) & 15;
  int jc = (id >> 10) & 31;
  int kc = id >> 15;
  int j  = jc * 16 + (l & 15);
  int c  = kc * 512 + kt * 32 + (l >> 4) * 8;
  const float* p = Wp + (size_t)j * Cz + c;
  short8 v;
  #pragma unroll
  for (int i = 0; i < 8; ++i) v[i] = (short)f2bf(p[i]);
  *(short8*)(wpp + (size_t)id * 8) = v;
}

__global__ __launch_bounds__(256) void precast_x(const float* __restrict__ x,
                                                 unsigned short* __restrict__ xb) {
  size_t id = ((size_t)blockIdx.x * 256 + threadIdx.x) * 4;
  float4 v = *(const float4*)(x + id);
  ushort4 o;
  o.x = f2bf(v.x); o.y = f2bf(v.y); o.z = f2bf(v.z); o.w = f2bf(v.w);
  *(ushort4*)(xb + id) = o;
}

// ---------------- kernel A: gates + cell state + a = o*tanh(mem) ----------------
// grid 256 (16 cells each), block 512 (8 waves). Tile: 64 batches x 64 gate-rows, K=1024.
template <bool PACKED>
__global__ __launch_bounds__(512)
void lstm_gates_kernel(const float* __restrict__ xf, const unsigned short* __restrict__ xb,
                       const float* __restrict__ Wi, const float* __restrict__ Wst,
                       const short* __restrict__ wpk,
                       const float* __restrict__ bstate, const int* __restrict__ lens,
                       const unsigned short* __restrict__ Hread,  // [64][512] bf16, h_{t-1}
                       float* __restrict__ cbuf,                  // [64][4096] fp32
                       unsigned short* __restrict__ abuf,         // [64][4096] bf16
                       float* __restrict__ final_c,
                       int t) {
  __shared__ __align__(16) short astage[2][64 * 16 * 8];  // 2 x 16KB, XOR-swizzled
  __shared__ float glds[64 * 65];                         // gate tile fp32, padded

  const int tid  = threadIdx.x;
  const int w    = blockIdx.x;
  const int lane = tid & 63;
  const int wv   = tid >> 6;
  const int lrow = lane & 15;
  const int lq   = lane >> 4;
  const int bt   = wv >> 1;        // batch 16-tile, 0..3
  const int ntb  = (wv & 1) * 2;   // gate-row 16-tile base, {0,2}

  floatx4 acc0 = {0.f, 0.f, 0.f, 0.f};
  floatx4 acc1 = {0.f, 0.f, 0.f, 0.f};

  auto stage = [&](int q, int buf) {
    const int k0 = q * 128;
    #pragma unroll
    for (int u = 0; u < 2; ++u) {
      int idx = u * 512 + tid;      // 0..1023
      int row = idx >> 4;           // batch 0..63
      int grp = idx & 15;           // 8-elem group within 128-k chunk
      int k = k0 + grp * 8;
      short8 val;
      if (k < Iz) {
        if (PACKED) {
          val = *(const short8*)(xb + ((size_t)row * Tz + t) * Iz + k);
        } else {
          const float* p = xf + ((size_t)row * Tz + t) * Iz + k;
          #pragma unroll
          for (int i = 0; i < 8; ++i) val[i] = (short)f2bf(p[i]);
        }
      } else {
        val = *(const short8*)(Hread + row * Hz + (k - Iz));
      }
      int phys = grp ^ (row & 15);
      *(short8*)(&astage[buf][(row * 16 + phys) * 8]) = val;
    }
  };

  stage(0, 0);
  __syncthreads();
  for (int q = 0; q < 8; ++q) {
    if (q < 7) stage(q + 1, (q + 1) & 1);
    const short* sb = astage[q & 1];
    #pragma unroll
    for (int ktl = 0; ktl < 4; ++ktl) {
      const int kt = q * 4 + ktl;
      int grp  = ktl * 4 + lq;
      int phys = grp ^ lrow;
      short8 afr = *(const short8*)(sb + ((bt * 16 + lrow) * 16 + phys) * 8);
      short8 bfr0, bfr1;
      if (PACKED) {
        const short* bp = wpk + ((((size_t)w * 4 + ntb) * 32 + kt) * 64 + lane) * 8;
        bfr0 = *(const short8*)bp;
        bfr1 = *(const short8*)(bp + (size_t)32 * 64 * 8);
      } else {
        #pragma unroll
        for (int hh = 0; hh < 2; ++hh) {
          int nt = ntb + hh;
          int r  = nt * Cz + w * 16 + lrow;
          int k  = kt * 32 + lq * 8;
          const float* p = (k < Iz) ? (Wi + (size_t)r * Iz + k)
                                    : (Wst + (size_t)r * Hz + (k - Iz));
          short8 v;
          #pragma unroll
          for (int i = 0; i < 8; ++i) v[i] = (short)f2bf(p[i]);
          if (hh == 0) bfr0 = v; else bfr1 = v;
        }
      }
      acc0 = __builtin_amdgcn_mfma_f32_16x16x32_bf16(afr, bfr0, acc0, 0, 0, 0);
      acc1 = __builtin_amdgcn_mfma_f32_16x16x32_bf16(afr, bfr1, acc1, 0, 0, 0);
    }
    __syncthreads();
  }

  {  // spill gate tile to LDS (C-frag layout: row=(lq)*4+r, col=lrow)
    const int b0 = bt * 16 + lq * 4;
    const int n0 = ntb * 16 + lrow;
    #pragma unroll
    for (int r = 0; r < 4; ++r) {
      glds[(b0 + r) * 65 + n0]      = acc0[r];
      glds[(b0 + r) * 65 + n0 + 16] = acc1[r];
    }
  }
  __syncthreads();
  {  // fp32 elementwise epilogue; thread owns cells (b, cc) and (b+32, cc)
    const int cc   = tid & 15;
    int b          = tid >> 4;   // 0..31
    const int cell = w * 16 + cc;
    const float bs0 = bstate[cell];
    const float bs1 = bstate[Cz + cell];
    const float bs2 = bstate[2 * Cz + cell];
    const float bs3 = bstate[3 * Cz + cell];
    #pragma unroll
    for (int hh = 0; hh < 2; ++hh, b += 32) {
      float g0 = glds[b * 65 + cc]      + bs0;   // i
      float g1 = glds[b * 65 + 16 + cc] + bs1;   // f
      float g2 = glds[b * 65 + 32 + cc] + bs2;   // m
      float g3 = glds[b * 65 + 48 + cc] + bs3;   // o
      float ig = sigmoidf_(g0);
      float fg = sigmoidf_(g1);
      float mi = tanhf(g2);
      float og = sigmoidf_(g3);
      size_t cidx = (size_t)b * Cz + cell;
      float c_old = cbuf[cidx];
      float mem = ig * mi + fg * c_old;
      mem = fminf(fmaxf(mem, -3.f), 3.f);
      bool active = t < lens[b];
      float c_new = active ? mem : c_old;
      cbuf[cidx] = c_new;
      abuf[cidx] = f2bf(og * tanhf(mem));
      if (t == Tz - 1) final_c[cidx] = c_new;
    }
  }
}

// ---------------- kernel B: projection (split-K atomics) + last-finisher finalize ----------
// grid 256 = kc(8, K-chunks of 512) x jc(32, 16 j each), block 256 (4 waves).
template <bool PACKED>
__global__ __launch_bounds__(256)
void lstm_proj_kernel(const unsigned short* __restrict__ abuf,
                      const float* __restrict__ Wp, const short* __restrict__ wpp,
                      const int* __restrict__ lens,
                      const unsigned short* __restrict__ Hold,
                      unsigned short* __restrict__ Hnew,
                      float* __restrict__ accum,   // [64][512] fp32, zeroed
                      int* __restrict__ done,      // [32]
                      float* __restrict__ outp,    // (B,T,H)
                      float* __restrict__ final_h,
                      int t) {
  __shared__ __align__(16) short alds[64 * 32 * 8];  // 32 KB, XOR-swizzled
  __shared__ int amLast;
  const int tid  = threadIdx.x;
  const int wg   = blockIdx.x;
  const int kc   = wg >> 5;
  const int jc   = wg & 31;
  const int lane = tid & 63;
  const int wv   = tid >> 6;
  const int lrow = lane & 15;
  const int lq   = lane >> 4;
  const int bt   = wv;  // batch 16-tile
  floatx4 acc = {0.f, 0.f, 0.f, 0.f};

  for (int ph = 0; ph < 2; ++ph) {  // two 256-wide K sub-chunks
    if (ph) __syncthreads();
    #pragma unroll
    for (int u = 0; u < 8; ++u) {
      int idx = u * 256 + tid;   // 0..2047
      int row = idx >> 5;        // batch
      int grp = idx & 31;
      short8 v = *(const short8*)((const short*)abuf + (size_t)row * Cz + kc * 512 + ph * 256 + grp * 8);
      int phys = grp ^ (row & 15);
      *(short8*)(&alds[(row * 32 + phys) * 8]) = v;
    }
    __syncthreads();
    #pragma unroll
    for (int ktl = 0; ktl < 8; ++ktl) {
      int kt   = ph * 8 + ktl;
      int grp  = ktl * 4 + lq;
      int phys = grp ^ lrow;
      short8 afr = *(const short8*)(&alds[((bt * 16 + lrow) * 32 + phys) * 8]);
      short8 bfr;
      if (PACKED) {
        bfr = *(const short8*)(wpp + ((((size_t)kc * 32 + jc) * 16 + kt) * 64 + lane) * 8);
      } else {
        int j = jc * 16 + lrow;
        int c = kc * 512 + kt * 32 + lq * 8;
        const float* p = Wp + (size_t)j * Cz + c;
        #pragma unroll
        for (int i = 0; i < 8; ++i) bfr[i] = (short)f2bf(p[i]);
      }
      acc = __builtin_amdgcn_mfma_f32_16x16x32_bf16(afr, bfr, acc, 0, 0, 0);
    }
  }
  {
    const int j  = jc * 16 + lrow;
    const int b0 = bt * 16 + lq * 4;
    #pragma unroll
    for (int r = 0; r < 4; ++r)
      unsafeAtomicAdd(&accum[(b0 + r) * Hz + j], acc[r]);
  }
  __threadfence();
  __syncthreads();
  if (tid == 0) {
    int old = __hip_atomic_fetch_add(&done[jc], 1, __ATOMIC_ACQ_REL, __HIP_MEMORY_SCOPE_AGENT);
    amLast = (old == 7) ? 1 : 0;
  }
  __syncthreads();
  if (amLast) {  // all 8 kc-partials landed for this jc: finalize 64x16
    #pragma unroll
    for (int u = 0; u < 4; ++u) {
      int e = u * 256 + tid;  // 0..1023
      int b = e >> 4;
      int j = jc * 16 + (e & 15);
      float v = __hip_atomic_load(&accum[b * Hz + j], __ATOMIC_RELAXED, __HIP_MEMORY_SCOPE_AGENT);
      v = fminf(fmaxf(v, -3.f), 3.f);
      bool active = t < lens[b];
      float h_old = bf2f(Hold[b * Hz + j]);
      float h_new = active ? v : h_old;
      outp[((size_t)b * Tz + t) * Hz + j] = active ? v : 0.f;
      Hnew[b * Hz + j] = f2bf(h_new);
      if (t == Tz - 1) final_h[b * Hz + j] = h_new;
      __hip_atomic_store(&accum[b * Hz + j], 0.f, __ATOMIC_RELAXED, __HIP_MEMORY_SCOPE_AGENT);
    }
    __threadfence();
    if (tid == 0)
      __hip_atomic_store(&done[jc], 0, __ATOMIC_RELEASE, __HIP_MEMORY_SCOPE_AGENT);
  }
}

// ---------------- launcher ----------------

extern "C" void kernel_launch(void* const* d_in, const int* in_sizes, int n_in,
                              void* d_out, int out_size, void* d_ws, size_t ws_size,
                              hipStream_t stream) {
  const float* x   = (const float*)d_in[0];
  const int* lens  = (const int*)d_in[1];
  const float* Wi  = (const float*)d_in[2];
  const float* Wst = (const float*)d_in[3];
  const float* bst = (const float*)d_in[4];
  const float* Wp  = (const float*)d_in[5];

  float* outp    = (float*)d_out;
  float* final_h = outp + (size_t)Bz * Tz * Hz;
  float* final_c = final_h + (size_t)Bz * Hz;

  char* ws = (char*)d_ws;
  const size_t OFF_H    = 0;                                              // 131072 B (2x h bf16)
  const size_t OFF_C    = OFF_H + 2 * (size_t)Bz * Hz * sizeof(unsigned short);
  const size_t OFF_ACC  = OFF_C + (size_t)Bz * Cz * sizeof(float);        // +1 MB
  const size_t OFF_DONE = OFF_ACC + (size_t)Bz * Hz * sizeof(float);      // +128 KB
  const size_t OFF_A    = OFF_DONE + 256;
  const size_t OFF_WPK  = OFF_A + (size_t)Bz * Cz * sizeof(unsigned short);    // +512 KB
  const size_t OFF_WPP  = OFF_WPK + (size_t)16384 * 1024 * sizeof(short);      // +32 MB
  const size_t OFF_XB   = OFF_WPP + (size_t)512 * 4096 * sizeof(short);        // +4 MB
  const size_t NEED     = OFF_XB + (size_t)Bz * Tz * Iz * sizeof(unsigned short); // +32 MB

  unsigned short* Hbuf = (unsigned short*)(ws + OFF_H);
  float* cbuf   = (float*)(ws + OFF_C);
  float* accum  = (float*)(ws + OFF_ACC);
  int* done     = (int*)(ws + OFF_DONE);
  unsigned short* abuf = (unsigned short*)(ws + OFF_A);
  short* wpk    = (short*)(ws + OFF_WPK);
  short* wpp    = (short*)(ws + OFF_WPP);
  unsigned short* xb = (unsigned short*)(ws + OFF_XB);

  const bool packed = (ws_size >= NEED);

  // zero h0, c0, accum, done counters
  hipMemsetAsync(ws, 0, OFF_A, stream);

  if (packed) {
    precast_wpk<<<8192, 256, 0, stream>>>(Wi, Wst, wpk);
    precast_wpp<<<1024, 256, 0, stream>>>(Wp, wpp);
    precast_x<<<16384, 256, 0, stream>>>(x, xb);
  }

  for (int t = 0; t < Tz; ++t) {
    const unsigned short* Hread = Hbuf + (size_t)(t & 1) * Bz * Hz;
    unsigned short* Hnew        = Hbuf + (size_t)((t & 1) ^ 1) * Bz * Hz;
    if (packed) {
      lstm_gates_kernel<true><<<256, 512, 0, stream>>>(x, xb, Wi, Wst, wpk, bst, lens,
                                                       Hread, cbuf, abuf, final_c, t);
      lstm_proj_kernel<true><<<256, 256, 0, stream>>>(abuf, Wp, wpp, lens, Hread, Hnew,
                                                      accum, done, outp, final_h, t);
    } else {
      lstm_gates_kernel<false><<<256, 512, 0, stream>>>(x, nullptr, Wi, Wst, nullptr, bst, lens,
                                                        Hread, cbuf, abuf, final_c, t);
      lstm_proj_kernel<false><<<256, 256, 0, stream>>>(abuf, Wp, nullptr, lens, Hread, Hnew,
                                                       accum, done, outp, final_h, t);
    }
  }
}